// Round 5
// baseline (294.801 us; speedup 1.0000x reference)
//
#include <hip/hip_runtime.h>
#include <hip/hip_bf16.h>
#include <stdint.h>

// Fused causal MHA, B=256,T=128,H=8,D=256,C=256. One block per (h,b).
// Round 5: LDS cut to 72KB (2 blocks/CU) by overlaying VT/O-strip/softmax
// scratch into dead regions; Q/K/O-strip rows restrided to 80B so b16
// writes and short8 reads are ~conflict-free (bank rotation 20/row).

#define TT 128
#define CC 256
#define DD 256

typedef __attribute__((ext_vector_type(8))) short short8;
typedef __attribute__((ext_vector_type(4))) float f32x4;

// LDS map (73728 B):
//   [0,16K)        W ring slot 0
//   [16K,32K)      W ring slot 1; overlays: O strip [128 t][80B] in PV phases
//                  (16384..26624), softmax scratch (26624..28672)
//   [32K,73728)    QK ring: 2 slots x 20480 (Q[128][80B] + K[128][80B]);
//                  P [128][256B swz] overwrites [32K,64K) after softmax;
//                  VT chunk [32 d][256B swz] at [64K,72K) during PV
#define LDS_W    0
#define LDS_QK   32768
#define LDS_P    32768
#define LDS_OS   16384
#define LDS_RED  26624
#define LDS_VT   65536
#define LDS_SIZE 73728

// ws map (needs >= 20054016 B)
#define WS_X    0u
#define WS_WQ   16777216u
#define WS_WK   (16777216u + 1048576u)
#define WS_WV   (16777216u + 2097152u)
#define WS_WP   (16777216u + 3145728u)

#define VMCNT0() asm volatile("s_waitcnt vmcnt(0)" ::: "memory")
#define VMCNT8() asm volatile("s_waitcnt vmcnt(8)" ::: "memory")
#define LGKM0()  asm volatile("s_waitcnt lgkmcnt(0)" ::: "memory")
#define BAR()    do { asm volatile("" ::: "memory"); __builtin_amdgcn_s_barrier(); asm volatile("" ::: "memory"); } while (0)

__device__ __forceinline__ unsigned short f2bf(float x) {
    union { float f; unsigned u; } v; v.f = x;
    unsigned r = v.u + 0x7FFFu + ((v.u >> 16) & 1u);
    return (unsigned short)(r >> 16);
}
__device__ __forceinline__ unsigned pk2(float a, float b) {
    return (unsigned)f2bf(a) | ((unsigned)f2bf(b) << 16);
}
__device__ __forceinline__ int swzr(int row, int byteInRow) {   // 512B/256B rows
    return byteInRow ^ ((row & 7) << 4);
}

typedef __attribute__((address_space(3))) uint32_t lds_u32;
typedef __attribute__((address_space(1))) const uint32_t glb_u32;

// ---------------- pre-convert: fp32 -> bf16, pre-swizzled 512B rows ----------------
__global__ void convert_pre(const float* __restrict__ x,
                            const float* __restrict__ Wq, const float* __restrict__ Wk,
                            const float* __restrict__ Wv, const float* __restrict__ Wp,
                            char* __restrict__ ws) {
    const int NX = 2097152, NW = 131072, NP = 16384;   // float4 counts
    const int total = NX + 3 * NW + NP;
    for (int i = blockIdx.x * blockDim.x + threadIdx.x; i < total;
         i += gridDim.x * blockDim.x) {
        const float4* src; size_t ob; int li;
        if (i < NX)              { src = (const float4*)x;  ob = WS_X;  li = i; }
        else if (i < NX + NW)    { src = (const float4*)Wq; ob = WS_WQ; li = i - NX; }
        else if (i < NX + 2*NW)  { src = (const float4*)Wk; ob = WS_WK; li = i - NX - NW; }
        else if (i < NX + 3*NW)  { src = (const float4*)Wv; ob = WS_WV; li = i - NX - 2*NW; }
        else                     { src = (const float4*)Wp; ob = WS_WP; li = i - NX - 3*NW; }
        float4 v = src[li];
        uint2 u; u.x = pk2(v.x, v.y); u.y = pk2(v.z, v.w);
        int row = li >> 6, c4 = li & 63;
        *(uint2*)(ws + ob + (size_t)row * 512 + ((c4 * 8) ^ ((row & 7) << 4))) = u;
    }
}

// ---------------- main fused kernel ----------------
__global__ __launch_bounds__(512, 2) void mha_fused(
    const char* __restrict__ ws,
    const float* __restrict__ bq, const float* __restrict__ bk,
    const float* __restrict__ bv, const float* __restrict__ bp,
    float* __restrict__ out)
{
    extern __shared__ __align__(16) char lds[];
    const int tid = threadIdx.x;
    const int w  = tid >> 6, l = tid & 63;
    const int lg = l >> 4, lr = l & 15;
    const int mq = w & 3, nh = w >> 2;        // 4 M-waves x 2 N-waves
    const int bid = blockIdx.x;
    const int h = bid >> 8, b = bid & 255;

    auto gl16 = [&](const char* g, int loff) {
        __builtin_amdgcn_global_load_lds((glb_u32*)g, (lds_u32*)(lds + loff), 16, 0, 0);
    };
    // chunk stream: 0..15 = Wq[c]/Wk[c] interleaved, 16..23 = Wv, 24..31 = Wp
    auto chunk_src = [&](int idx) -> const char* {
        if (idx < 16) {
            int c = idx >> 1;
            return ws + ((idx & 1) ? WS_WK : WS_WQ) + (size_t)h * 131072 + (size_t)c * 16384;
        } else if (idx < 24) {
            return ws + WS_WV + (size_t)h * 131072 + (size_t)(idx - 16) * 16384;
        }
        return ws + WS_WP + (size_t)(idx - 24) * 16384;
    };
    auto issue_chunk = [&](int idx) {
        const char* g = chunk_src(idx) + tid * 16;
        int loff = LDS_W + (idx & 1) * 16384 + tid * 16;
        gl16(g, loff);
        gl16(g + 8192, loff + 8192);
    };

    // ---- X as A-fragments in registers (32 VGPR), direct per-lane loads ----
    short8 xf[2][8];
    {
        const char* xp = ws + WS_X + (size_t)b * 65536;
        #pragma unroll
        for (int mt = 0; mt < 2; ++mt) {
            int t = mq * 32 + mt * 16 + lr;
            #pragma unroll
            for (int ks = 0; ks < 8; ++ks)
                xf[mt][ks] = *(const short8*)(xp + t * 512 + swzr(t, ks * 64 + lg * 16));
        }
    }
    issue_chunk(0);
    VMCNT0(); BAR();

    // proj: acc[mt] += X[32t x 256] * Wchunk[32 rows]^T (wave tile 32t x 16n)
    auto proj_mm = [&](int slot, f32x4* acc) {
        const char* Wb = lds + LDS_W + slot * 16384;
        const int br = nh * 16 + lr;
        #pragma unroll
        for (int ks = 0; ks < 8; ++ks) {
            short8 b0 = *(const short8*)(Wb + br * 512 + swzr(br, ks * 64 + lg * 16));
            acc[0] = __builtin_amdgcn_mfma_f32_16x16x32_bf16(xf[0][ks], b0, acc[0], 0, 0, 0);
            acc[1] = __builtin_amdgcn_mfma_f32_16x16x32_bf16(xf[1][ks], b0, acc[1], 0, 0, 0);
        }
    };

    f32x4 sacc[2][4];
    #pragma unroll
    for (int i = 0; i < 2; ++i)
        #pragma unroll
        for (int j = 0; j < 4; ++j) sacc[i][j] = f32x4{0.f,0.f,0.f,0.f};

    // ---- QK phases ----
    #pragma unroll
    for (int c = 0; c < 8; ++c) {
        char* qslot = lds + LDS_QK + (c & 1) * 20480;   // Q [128][80B] + K [128][80B]
        // Q_c : consumes chunk 2c (slot 0), issues 2c+1
        issue_chunk(2 * c + 1);
        {
            f32x4 acc[2] = {f32x4{0.f,0.f,0.f,0.f}, f32x4{0.f,0.f,0.f,0.f}};
            proj_mm(0, acc);
            float bias = bq[h * DD + c * 32 + nh * 16 + lr];
            #pragma unroll
            for (int mt = 0; mt < 2; ++mt)
                #pragma unroll
                for (int r = 0; r < 4; ++r) {
                    int t = mq * 32 + mt * 16 + lg * 4 + r;
                    *(unsigned short*)(qslot + t * 80 + (nh * 16 + lr) * 2)
                        = f2bf((acc[mt][r] + bias) * 0.0625f);
                }
        }
        LGKM0(); VMCNT0(); BAR();
        // K_c : consumes chunk 2c+1 (slot 1), issues 2c+2
        issue_chunk(2 * c + 2);
        {
            f32x4 acc[2] = {f32x4{0.f,0.f,0.f,0.f}, f32x4{0.f,0.f,0.f,0.f}};
            proj_mm(1, acc);
            float bias = bk[h * DD + c * 32 + nh * 16 + lr];
            char* ksl = qslot + 10240;
            #pragma unroll
            for (int mt = 0; mt < 2; ++mt)
                #pragma unroll
                for (int r = 0; r < 4; ++r) {
                    int s = mq * 32 + mt * 16 + lg * 4 + r;
                    *(unsigned short*)(ksl + s * 80 + (nh * 16 + lr) * 2)
                        = f2bf(acc[mt][r] + bias);
                }
        }
        LGKM0(); VMCNT0(); BAR();
        // S += Q_c K_c^T (reads slot c&1; slot (c+1)&1 written next -> race-free)
        {
            const char* qs  = qslot;
            const char* ks2 = qslot + 10240;
            short8 qa[2], kb[4];
            #pragma unroll
            for (int mt = 0; mt < 2; ++mt) {
                int row = mq * 32 + mt * 16 + lr;
                qa[mt] = *(const short8*)(qs + row * 80 + lg * 16);
            }
            #pragma unroll
            for (int nt = 0; nt < 4; ++nt) {
                int srow = nh * 64 + nt * 16 + lr;
                kb[nt] = *(const short8*)(ks2 + srow * 80 + lg * 16);
            }
            #pragma unroll
            for (int mt = 0; mt < 2; ++mt)
                #pragma unroll
                for (int nt = 0; nt < 4; ++nt)
                    sacc[mt][nt] = __builtin_amdgcn_mfma_f32_16x16x32_bf16(qa[mt], kb[nt], sacc[mt][nt], 0, 0, 0);
        }
    }

    // ---- softmax (scratch in W slot 1, free: chunk 15 consumed, 16 -> slot 0) ----
    float* redM = (float*)(lds + LDS_RED);
    float* redS = redM + 256;
    {
        float rmax[2][4];
        #pragma unroll
        for (int mt = 0; mt < 2; ++mt)
            #pragma unroll
            for (int r = 0; r < 4; ++r) {
                int t = mq * 32 + mt * 16 + lg * 4 + r;
                float m = -1e30f;
                #pragma unroll
                for (int nt = 0; nt < 4; ++nt) {
                    int s = nh * 64 + nt * 16 + lr;
                    if (s > t) sacc[mt][nt][r] = -1e30f;
                    m = fmaxf(m, sacc[mt][nt][r]);
                }
                m = fmaxf(m, __shfl_xor(m, 1));
                m = fmaxf(m, __shfl_xor(m, 2));
                m = fmaxf(m, __shfl_xor(m, 4));
                m = fmaxf(m, __shfl_xor(m, 8));
                rmax[mt][r] = m;
            }
        if (lr == 0) {
            #pragma unroll
            for (int mt = 0; mt < 2; ++mt)
                #pragma unroll
                for (int r = 0; r < 4; ++r)
                    redM[nh * 128 + mq * 32 + mt * 16 + lg * 4 + r] = rmax[mt][r];
        }
        LGKM0(); BAR();
        float rsum[2][4];
        #pragma unroll
        for (int mt = 0; mt < 2; ++mt)
            #pragma unroll
            for (int r = 0; r < 4; ++r) {
                int t = mq * 32 + mt * 16 + lg * 4 + r;
                float m = fmaxf(redM[t], redM[128 + t]);
                float ssum = 0.f;
                #pragma unroll
                for (int nt = 0; nt < 4; ++nt) {
                    float p = __expf(sacc[mt][nt][r] - m);
                    sacc[mt][nt][r] = p;
                    ssum += p;
                }
                ssum += __shfl_xor(ssum, 1);
                ssum += __shfl_xor(ssum, 2);
                ssum += __shfl_xor(ssum, 4);
                ssum += __shfl_xor(ssum, 8);
                rsum[mt][r] = ssum;
            }
        if (lr == 0) {
            #pragma unroll
            for (int mt = 0; mt < 2; ++mt)
                #pragma unroll
                for (int r = 0; r < 4; ++r)
                    redS[nh * 128 + mq * 32 + mt * 16 + lg * 4 + r] = rsum[mt][r];
        }
        LGKM0(); BAR();
        // P -> [32K,64K): [128 t][256B rows], swizzled (overwrites QK ring)
        #pragma unroll
        for (int mt = 0; mt < 2; ++mt)
            #pragma unroll
            for (int r = 0; r < 4; ++r) {
                int t = mq * 32 + mt * 16 + lg * 4 + r;
                float inv = 1.0f / (redS[t] + redS[128 + t]);
                #pragma unroll
                for (int nt = 0; nt < 4; ++nt) {
                    int s = nh * 64 + nt * 16 + lr;
                    *(unsigned short*)(lds + LDS_P + t * 256 + swzr(t, s * 2))
                        = f2bf(sacc[mt][nt][r] * inv);
                }
            }
    }
    LGKM0(); VMCNT0(); BAR();   // P visible; chunk 16 (Wv0) arrived

    // ---- V phases: V kept in registers (bf16-packed C-layout) ----
    uint2 vreg[8][2];
    #pragma unroll
    for (int vc = 0; vc < 8; ++vc) {
        issue_chunk(17 + vc);                 // 17..24 (Wv1..7, Wp0)
        f32x4 acc[2] = {f32x4{0.f,0.f,0.f,0.f}, f32x4{0.f,0.f,0.f,0.f}};
        proj_mm(vc & 1, acc);
        float bias = bv[h * DD + vc * 32 + nh * 16 + lr];
        #pragma unroll
        for (int mt = 0; mt < 2; ++mt) {
            vreg[vc][mt].x = pk2(acc[mt][0] + bias, acc[mt][1] + bias);
            vreg[vc][mt].y = pk2(acc[mt][2] + bias, acc[mt][3] + bias);
        }
        LGKM0(); VMCNT0(); BAR();
    }

    // ---- PV with per-chunk O transpose through the 80B-stride strip ----
    // Live LDS: Wp0 in slot0 [0,16K); O strip [16K,26.6K); P [32K,64K); VT [64K,72K).
    short8 pa[2][4];
    #pragma unroll
    for (int mt = 0; mt < 2; ++mt) {
        int row = mq * 32 + mt * 16 + lr;
        #pragma unroll
        for (int ks = 0; ks < 4; ++ks)
            pa[mt][ks] = *(const short8*)(lds + LDS_P + row * 256 + swzr(row, ks * 64 + lg * 16));
    }
    short8 of[2][8];
    const int dl = nh * 16 + lr;
    #pragma unroll
    for (int c = 0; c < 8; ++c) {
        // window A: write VT_c; read back of_{c-1} from the O strip
        #pragma unroll
        for (int mt = 0; mt < 2; ++mt) {
            int s0 = mq * 32 + mt * 16 + lg * 4;
            *(uint2*)(lds + LDS_VT + dl * 256 + swzr(dl, s0 * 2)) = vreg[c][mt];
        }
        if (c > 0) {
            #pragma unroll
            for (int mt = 0; mt < 2; ++mt) {
                int row = mq * 32 + mt * 16 + lr;
                of[mt][c - 1] = *(const short8*)(lds + LDS_OS + row * 80 + lg * 16);
            }
        }
        LGKM0(); BAR();
        // window B: PV MFMAs (P x VT_c) ; write O d-band c to the strip
        f32x4 oacc[2] = {f32x4{0.f,0.f,0.f,0.f}, f32x4{0.f,0.f,0.f,0.f}};
        #pragma unroll
        for (int ks = 0; ks < 4; ++ks) {
            short8 vb = *(const short8*)(lds + LDS_VT + dl * 256 + swzr(dl, ks * 64 + lg * 16));
            oacc[0] = __builtin_amdgcn_mfma_f32_16x16x32_bf16(pa[0][ks], vb, oacc[0], 0, 0, 0);
            oacc[1] = __builtin_amdgcn_mfma_f32_16x16x32_bf16(pa[1][ks], vb, oacc[1], 0, 0, 0);
        }
        #pragma unroll
        for (int mt = 0; mt < 2; ++mt)
            #pragma unroll
            for (int r = 0; r < 4; ++r) {
                int t = mq * 32 + mt * 16 + lg * 4 + r;
                *(unsigned short*)(lds + LDS_OS + t * 80 + (nh * 16 + lr) * 2)
                    = f2bf(oacc[mt][r]);
            }
        LGKM0(); BAR();
    }
    // tail: read of_{7}; barrier before OUT (chunk 25 overwrites the strip region)
    #pragma unroll
    for (int mt = 0; mt < 2; ++mt) {
        int row = mq * 32 + mt * 16 + lr;
        of[mt][7] = *(const short8*)(lds + LDS_OS + row * 80 + lg * 16);
    }
    LGKM0(); BAR();
    VMCNT0();   // chunk 24 (Wp0, issued in V phase 7) arrived

    // ---- OUT = O * Wp^T + bp -> global fp32 ----
    #pragma unroll
    for (int m = 0; m < 8; ++m) {
        if (m < 7) issue_chunk(25 + m);       // 25..31
        f32x4 acc[2] = {f32x4{0.f,0.f,0.f,0.f}, f32x4{0.f,0.f,0.f,0.f}};
        {
            const char* Wb = lds + LDS_W + (m & 1) * 16384;
            const int br = nh * 16 + lr;
            #pragma unroll
            for (int ks = 0; ks < 8; ++ks) {
                short8 b0 = *(const short8*)(Wb + br * 512 + swzr(br, ks * 64 + lg * 16));
                acc[0] = __builtin_amdgcn_mfma_f32_16x16x32_bf16(of[0][ks], b0, acc[0], 0, 0, 0);
                acc[1] = __builtin_amdgcn_mfma_f32_16x16x32_bf16(of[1][ks], b0, acc[1], 0, 0, 0);
            }
        }
        int e = m * 32 + nh * 16 + lr;
        float bias = bp[e];
        #pragma unroll
        for (int mt = 0; mt < 2; ++mt)
            #pragma unroll
            for (int r = 0; r < 4; ++r) {
                int t = mq * 32 + mt * 16 + lg * 4 + r;
                out[((size_t)bid * TT + t) * DD + e] = acc[mt][r] + bias;
            }
        if (m < 7) { LGKM0(); VMCNT8(); BAR(); }
    }
}

extern "C" void kernel_launch(void* const* d_in, const int* in_sizes, int n_in,
                              void* d_out, int out_size, void* d_ws, size_t ws_size,
                              hipStream_t stream) {
    (void)in_sizes; (void)n_in; (void)out_size; (void)ws_size; // needs ws_size >= 20054016
    const float* x  = (const float*)d_in[0];
    const float* Wq = (const float*)d_in[1];
    const float* bq = (const float*)d_in[2];
    const float* Wk = (const float*)d_in[3];
    const float* bk = (const float*)d_in[4];
    const float* Wv = (const float*)d_in[5];
    const float* bv = (const float*)d_in[6];
    const float* Wp = (const float*)d_in[7];
    const float* bp = (const float*)d_in[8];
    char* ws = (char*)d_ws;

    convert_pre<<<dim3(2048), dim3(256), 0, stream>>>(x, Wq, Wk, Wv, Wp, ws);
    hipFuncSetAttribute((const void*)mha_fused,
                        hipFuncAttributeMaxDynamicSharedMemorySize, LDS_SIZE);
    mha_fused<<<dim3(2048), dim3(512), LDS_SIZE, stream>>>(
        ws, bq, bk, bv, bp, (float*)d_out);
}

// Round 6
// 285.102 us; speedup vs baseline: 1.0340x; 1.0340x over previous
//
#include <hip/hip_runtime.h>
#include <hip/hip_bf16.h>
#include <stdint.h>

// Fused causal MHA, B=256,T=128,H=8,D=256,C=256. One block per (h,b).
// Round 6: accept 1 block/CU (register-limited); deep-pipeline within the
// block: 3x32KB W pair-ring (Wq/Wk interleaved), 2-pair prefetch distance,
// counted vmcnt(4) (never 0 in main loop), merged Q+K phases (1 barrier),
// barrier-light V/OUT phases.

#define TT 128
#define CC 256
#define DD 256

typedef __attribute__((ext_vector_type(8))) short short8;
typedef __attribute__((ext_vector_type(4))) float f32x4;

// LDS map (159744 B):
//   [0,96K)            W pair ring: 3 x 32KB (each pair = 2 x 16KB chunk)
//   [96K,136K)         QK slots: 2 x 20480 (Q[128][80B] + K[128][80B])
//                      P [128][256B swz] overwrites [96K,128K) after softmax
//   [136K,144K)        VT chunk [32 d][256B swz]
//   [144K,154K)        O transpose strip [128 t][80B]
//   [154K,156K)        softmax reduce scratch
#define LDS_W    0
#define LDS_QK   98304
#define LDS_P    98304
#define LDS_VT   139264
#define LDS_OS   147456
#define LDS_RED  157696
#define LDS_SIZE 159744

// ws map (needs >= 20051968 B)
#define WS_X    0u
#define WS_QK   16777216u              // 8 heads x 8 pairs x 32KB (Wq|Wk chunk-interleaved)
#define WS_WV   (16777216u + 2097152u) // 8 heads x 128KB
#define WS_WP   (16777216u + 3145728u) // 128KB

#define VMCNT4() asm volatile("s_waitcnt vmcnt(4)" ::: "memory")
#define VMCNT0() asm volatile("s_waitcnt vmcnt(0)" ::: "memory")
#define LGKM0()  asm volatile("s_waitcnt lgkmcnt(0)" ::: "memory")
#define BAR()    do { asm volatile("" ::: "memory"); __builtin_amdgcn_s_barrier(); asm volatile("" ::: "memory"); } while (0)

__device__ __forceinline__ unsigned short f2bf(float x) {
    union { float f; unsigned u; } v; v.f = x;
    unsigned r = v.u + 0x7FFFu + ((v.u >> 16) & 1u);
    return (unsigned short)(r >> 16);
}
__device__ __forceinline__ unsigned pk2(float a, float b) {
    return (unsigned)f2bf(a) | ((unsigned)f2bf(b) << 16);
}
__device__ __forceinline__ int swzr(int row, int byteInRow) {   // 512B/256B rows
    return byteInRow ^ ((row & 7) << 4);
}

typedef __attribute__((address_space(3))) uint32_t lds_u32;
typedef __attribute__((address_space(1))) const uint32_t glb_u32;

// ---------------- pre-convert: fp32 -> bf16, pre-swizzled rows ----------------
__global__ void convert_pre(const float* __restrict__ x,
                            const float* __restrict__ Wq, const float* __restrict__ Wk,
                            const float* __restrict__ Wv, const float* __restrict__ Wp,
                            char* __restrict__ ws) {
    const int NX = 2097152, NW = 131072, NP = 16384;   // float4 counts
    const int total = NX + 3 * NW + NP;
    for (int i = blockIdx.x * blockDim.x + threadIdx.x; i < total;
         i += gridDim.x * blockDim.x) {
        float4 v; size_t dst; int row, c4;
        if (i < NX) {
            v = ((const float4*)x)[i];
            row = i >> 6; c4 = i & 63;
            dst = WS_X + (size_t)row * 512 + ((c4 * 8) ^ ((row & 7) << 4));
        } else if (i < NX + NW) {               // Wq -> pair half 0
            int li = i - NX;
            v = ((const float4*)Wq)[li];
            row = li >> 6; c4 = li & 63;
            dst = WS_QK + (size_t)(row >> 8) * 262144 + (size_t)((row >> 5) & 7) * 32768
                + (size_t)(row & 31) * 512 + ((c4 * 8) ^ ((row & 7) << 4));
        } else if (i < NX + 2 * NW) {           // Wk -> pair half 1
            int li = i - NX - NW;
            v = ((const float4*)Wk)[li];
            row = li >> 6; c4 = li & 63;
            dst = WS_QK + (size_t)(row >> 8) * 262144 + (size_t)((row >> 5) & 7) * 32768
                + 16384 + (size_t)(row & 31) * 512 + ((c4 * 8) ^ ((row & 7) << 4));
        } else if (i < NX + 3 * NW) {           // Wv contiguous
            int li = i - NX - 2 * NW;
            v = ((const float4*)Wv)[li];
            row = li >> 6; c4 = li & 63;
            dst = WS_WV + (size_t)row * 512 + ((c4 * 8) ^ ((row & 7) << 4));
        } else {                                // Wp contiguous
            int li = i - NX - 3 * NW;
            v = ((const float4*)Wp)[li];
            row = li >> 6; c4 = li & 63;
            dst = WS_WP + (size_t)row * 512 + ((c4 * 8) ^ ((row & 7) << 4));
        }
        uint2 u; u.x = pk2(v.x, v.y); u.y = pk2(v.z, v.w);
        *(uint2*)(ws + dst) = u;
    }
}

// ---------------- main fused kernel ----------------
__global__ __launch_bounds__(512, 2) void mha_fused(
    const char* __restrict__ ws,
    const float* __restrict__ bq, const float* __restrict__ bk,
    const float* __restrict__ bv, const float* __restrict__ bp,
    float* __restrict__ out)
{
    extern __shared__ __align__(16) char lds[];
    const int tid = threadIdx.x;
    const int w  = tid >> 6, l = tid & 63;
    const int lg = l >> 4, lr = l & 15;
    const int mq = w & 3, nh = w >> 2;        // 4 M-waves x 2 N-waves
    const int bid = blockIdx.x;
    const int h = bid >> 8, b = bid & 255;

    auto gl16 = [&](const char* g, int loff) {
        __builtin_amdgcn_global_load_lds((glb_u32*)g, (lds_u32*)(lds + loff), 16, 0, 0);
    };
    // pairs: 0..7 = (Wq_c|Wk_c), 8..11 = Wv, 12..15 = Wp  (32KB each)
    auto pair_src = [&](int p) -> const char* {
        if (p < 8)  return ws + WS_QK + (size_t)h * 262144 + (size_t)p * 32768;
        if (p < 12) return ws + WS_WV + (size_t)h * 131072 + (size_t)(p - 8) * 32768;
        return ws + WS_WP + (size_t)(p - 12) * 32768;
    };
    auto issue_pair = [&](int p) {           // 4 x 16B loads per thread
        const char* g = pair_src(p) + tid * 16;
        int lo = LDS_W + (p % 3) * 32768 + tid * 16;
        gl16(g, lo);            gl16(g + 8192,  lo + 8192);
        gl16(g + 16384, lo + 16384); gl16(g + 24576, lo + 24576);
    };

    // ---- X as A-fragments in registers (64 VGPR) ----
    short8 xf[2][8];
    {
        const char* xp = ws + WS_X + (size_t)b * 65536;
        #pragma unroll
        for (int mt = 0; mt < 2; ++mt) {
            int t = mq * 32 + mt * 16 + lr;
            #pragma unroll
            for (int ks = 0; ks < 8; ++ks)
                xf[mt][ks] = *(const short8*)(xp + t * 512 + swzr(t, ks * 64 + lg * 16));
        }
    }
    issue_pair(0);
    issue_pair(1);
    VMCNT4(); BAR();           // X + pair0 done; pair1 in flight

    // proj: acc[mt] += X[32t x 256] * Wchunk[32 rows]^T (wave tile 32t x 16n)
    auto proj_mm = [&](const char* Wb, f32x4* acc) {
        const int br = nh * 16 + lr;
        #pragma unroll
        for (int ks = 0; ks < 8; ++ks) {
            short8 b0 = *(const short8*)(Wb + br * 512 + swzr(br, ks * 64 + lg * 16));
            acc[0] = __builtin_amdgcn_mfma_f32_16x16x32_bf16(xf[0][ks], b0, acc[0], 0, 0, 0);
            acc[1] = __builtin_amdgcn_mfma_f32_16x16x32_bf16(xf[1][ks], b0, acc[1], 0, 0, 0);
        }
    };

    f32x4 sacc[2][4];
    #pragma unroll
    for (int i = 0; i < 2; ++i)
        #pragma unroll
        for (int j = 0; j < 4; ++j) sacc[i][j] = f32x4{0.f,0.f,0.f,0.f};

    // ---- merged QK phases: one barrier per c ----
    #pragma unroll
    for (int c = 0; c < 8; ++c) {
        issue_pair(c + 2);                            // pairs 2..9
        char* qslot = lds + LDS_QK + (c & 1) * 20480;
        const char* Wpair = lds + LDS_W + (c % 3) * 32768;
        {   // Q_c
            f32x4 acc[2] = {f32x4{0.f,0.f,0.f,0.f}, f32x4{0.f,0.f,0.f,0.f}};
            proj_mm(Wpair, acc);
            float bias = bq[h * DD + c * 32 + nh * 16 + lr];
            #pragma unroll
            for (int mt = 0; mt < 2; ++mt)
                #pragma unroll
                for (int r = 0; r < 4; ++r) {
                    int t = mq * 32 + mt * 16 + lg * 4 + r;
                    *(unsigned short*)(qslot + t * 80 + (nh * 16 + lr) * 2)
                        = f2bf((acc[mt][r] + bias) * 0.0625f);
                }
        }
        {   // K_c
            f32x4 acc[2] = {f32x4{0.f,0.f,0.f,0.f}, f32x4{0.f,0.f,0.f,0.f}};
            proj_mm(Wpair + 16384, acc);
            float bias = bk[h * DD + c * 32 + nh * 16 + lr];
            char* ksl = qslot + 10240;
            #pragma unroll
            for (int mt = 0; mt < 2; ++mt)
                #pragma unroll
                for (int r = 0; r < 4; ++r) {
                    int s = mq * 32 + mt * 16 + lg * 4 + r;
                    *(unsigned short*)(ksl + s * 80 + (nh * 16 + lr) * 2)
                        = f2bf(acc[mt][r] + bias);
                }
        }
        LGKM0(); VMCNT4(); BAR();                     // pair c+1 done; c+2 in flight
        // S += Q_c K_c^T
        {
            const char* qs  = qslot;
            const char* ks2 = qslot + 10240;
            short8 qa[2], kb[4];
            #pragma unroll
            for (int mt = 0; mt < 2; ++mt) {
                int row = mq * 32 + mt * 16 + lr;
                qa[mt] = *(const short8*)(qs + row * 80 + lg * 16);
            }
            #pragma unroll
            for (int nt = 0; nt < 4; ++nt) {
                int srow = nh * 64 + nt * 16 + lr;
                kb[nt] = *(const short8*)(ks2 + srow * 80 + lg * 16);
            }
            #pragma unroll
            for (int mt = 0; mt < 2; ++mt)
                #pragma unroll
                for (int nt = 0; nt < 4; ++nt)
                    sacc[mt][nt] = __builtin_amdgcn_mfma_f32_16x16x32_bf16(qa[mt], kb[nt], sacc[mt][nt], 0, 0, 0);
        }
    }

    // ---- softmax ----
    float* redM = (float*)(lds + LDS_RED);
    float* redS = redM + 256;
    {
        float rmax[2][4];
        #pragma unroll
        for (int mt = 0; mt < 2; ++mt)
            #pragma unroll
            for (int r = 0; r < 4; ++r) {
                int t = mq * 32 + mt * 16 + lg * 4 + r;
                float m = -1e30f;
                #pragma unroll
                for (int nt = 0; nt < 4; ++nt) {
                    int s = nh * 64 + nt * 16 + lr;
                    if (s > t) sacc[mt][nt][r] = -1e30f;
                    m = fmaxf(m, sacc[mt][nt][r]);
                }
                m = fmaxf(m, __shfl_xor(m, 1));
                m = fmaxf(m, __shfl_xor(m, 2));
                m = fmaxf(m, __shfl_xor(m, 4));
                m = fmaxf(m, __shfl_xor(m, 8));
                rmax[mt][r] = m;
            }
        if (lr == 0) {
            #pragma unroll
            for (int mt = 0; mt < 2; ++mt)
                #pragma unroll
                for (int r = 0; r < 4; ++r)
                    redM[nh * 128 + mq * 32 + mt * 16 + lg * 4 + r] = rmax[mt][r];
        }
        LGKM0(); BAR();
        float rsum[2][4];
        #pragma unroll
        for (int mt = 0; mt < 2; ++mt)
            #pragma unroll
            for (int r = 0; r < 4; ++r) {
                int t = mq * 32 + mt * 16 + lg * 4 + r;
                float m = fmaxf(redM[t], redM[128 + t]);
                float ssum = 0.f;
                #pragma unroll
                for (int nt = 0; nt < 4; ++nt) {
                    float p = __expf(sacc[mt][nt][r] - m);
                    sacc[mt][nt][r] = p;
                    ssum += p;
                }
                ssum += __shfl_xor(ssum, 1);
                ssum += __shfl_xor(ssum, 2);
                ssum += __shfl_xor(ssum, 4);
                ssum += __shfl_xor(ssum, 8);
                rsum[mt][r] = ssum;
            }
        if (lr == 0) {
            #pragma unroll
            for (int mt = 0; mt < 2; ++mt)
                #pragma unroll
                for (int r = 0; r < 4; ++r)
                    redS[nh * 128 + mq * 32 + mt * 16 + lg * 4 + r] = rsum[mt][r];
        }
        LGKM0(); BAR();
        // P -> [96K,128K): [128 t][256B rows] swizzled (QK slots dead)
        #pragma unroll
        for (int mt = 0; mt < 2; ++mt)
            #pragma unroll
            for (int r = 0; r < 4; ++r) {
                int t = mq * 32 + mt * 16 + lg * 4 + r;
                float inv = 1.0f / (redS[t] + redS[128 + t]);
                #pragma unroll
                for (int nt = 0; nt < 4; ++nt) {
                    int s = nh * 64 + nt * 16 + lr;
                    *(unsigned short*)(lds + LDS_P + t * 256 + swzr(t, s * 2))
                        = f2bf(sacc[mt][nt][r] * inv);
                }
            }
    }
    LGKM0(); BAR();            // P visible (pair 8 already ensured done)

    // ---- V phases: register-only consumers; barrier every 2nd phase ----
    uint2 vreg[8][2];
    #pragma unroll
    for (int vc = 0; vc < 8; ++vc) {
        if ((vc & 1) == 0) issue_pair(10 + (vc >> 1));   // 10,11,12,13
        const char* Wb = lds + LDS_W + ((8 + (vc >> 1)) % 3) * 32768 + (vc & 1) * 16384;
        f32x4 acc[2] = {f32x4{0.f,0.f,0.f,0.f}, f32x4{0.f,0.f,0.f,0.f}};
        proj_mm(Wb, acc);
        float bias = bv[h * DD + vc * 32 + nh * 16 + lr];
        #pragma unroll
        for (int mt = 0; mt < 2; ++mt) {
            vreg[vc][mt].x = pk2(acc[mt][0] + bias, acc[mt][1] + bias);
            vreg[vc][mt].y = pk2(acc[mt][2] + bias, acc[mt][3] + bias);
        }
        if (vc & 1) { VMCNT4(); BAR(); }
    }

    // ---- PV with per-chunk O transpose through the 80B-stride strip ----
    short8 pa[2][4];
    #pragma unroll
    for (int mt = 0; mt < 2; ++mt) {
        int row = mq * 32 + mt * 16 + lr;
        #pragma unroll
        for (int ks = 0; ks < 4; ++ks)
            pa[mt][ks] = *(const short8*)(lds + LDS_P + row * 256 + swzr(row, ks * 64 + lg * 16));
    }
    short8 of[2][8];
    const int dl = nh * 16 + lr;
    #pragma unroll
    for (int c = 0; c < 8; ++c) {
        // window A: write VT_c; read back of_{c-1} from the O strip
        #pragma unroll
        for (int mt = 0; mt < 2; ++mt) {
            int s0 = mq * 32 + mt * 16 + lg * 4;
            *(uint2*)(lds + LDS_VT + dl * 256 + swzr(dl, s0 * 2)) = vreg[c][mt];
        }
        if (c > 0) {
            #pragma unroll
            for (int mt = 0; mt < 2; ++mt) {
                int row = mq * 32 + mt * 16 + lr;
                of[mt][c - 1] = *(const short8*)(lds + LDS_OS + row * 80 + lg * 16);
            }
        }
        LGKM0(); BAR();
        // window B: PV MFMAs ; write O d-band c to the strip
        f32x4 oacc[2] = {f32x4{0.f,0.f,0.f,0.f}, f32x4{0.f,0.f,0.f,0.f}};
        #pragma unroll
        for (int ks = 0; ks < 4; ++ks) {
            short8 vb = *(const short8*)(lds + LDS_VT + dl * 256 + swzr(dl, ks * 64 + lg * 16));
            oacc[0] = __builtin_amdgcn_mfma_f32_16x16x32_bf16(pa[0][ks], vb, oacc[0], 0, 0, 0);
            oacc[1] = __builtin_amdgcn_mfma_f32_16x16x32_bf16(pa[1][ks], vb, oacc[1], 0, 0, 0);
        }
        #pragma unroll
        for (int mt = 0; mt < 2; ++mt)
            #pragma unroll
            for (int r = 0; r < 4; ++r) {
                int t = mq * 32 + mt * 16 + lg * 4 + r;
                *(unsigned short*)(lds + LDS_OS + t * 80 + (nh * 16 + lr) * 2)
                    = f2bf(oacc[mt][r]);
            }
        LGKM0(); BAR();
    }
    // tail: read of_{7} (strip untouched afterwards; no extra barrier needed)
    #pragma unroll
    for (int mt = 0; mt < 2; ++mt) {
        int row = mq * 32 + mt * 16 + lr;
        of[mt][7] = *(const short8*)(lds + LDS_OS + row * 80 + lg * 16);
    }

    // ---- OUT = O * Wp^T + bp -> global fp32 (pairs 12..15) ----
    #pragma unroll
    for (int m = 0; m < 8; ++m) {
        if (m == 0) issue_pair(14);
        if (m == 2) issue_pair(15);
        const char* Wb = lds + LDS_W + ((12 + (m >> 1)) % 3) * 32768 + (m & 1) * 16384;
        f32x4 acc[2] = {f32x4{0.f,0.f,0.f,0.f}, f32x4{0.f,0.f,0.f,0.f}};
        {
            const int br = nh * 16 + lr;
            #pragma unroll
            for (int ks = 0; ks < 8; ++ks) {
                short8 b0 = *(const short8*)(Wb + br * 512 + swzr(br, ks * 64 + lg * 16));
                acc[0] = __builtin_amdgcn_mfma_f32_16x16x32_bf16(of[0][ks], b0, acc[0], 0, 0, 0);
                acc[1] = __builtin_amdgcn_mfma_f32_16x16x32_bf16(of[1][ks], b0, acc[1], 0, 0, 0);
            }
        }
        int e = m * 32 + nh * 16 + lr;
        float bias = bp[e];
        #pragma unroll
        for (int mt = 0; mt < 2; ++mt)
            #pragma unroll
            for (int r = 0; r < 4; ++r) {
                int t = mq * 32 + mt * 16 + lg * 4 + r;
                out[((size_t)bid * TT + t) * DD + e] = acc[mt][r] + bias;
            }
        if (m == 1 || m == 3) { VMCNT4(); BAR(); }
        else if (m == 5)      { VMCNT0(); BAR(); }
    }
}

extern "C" void kernel_launch(void* const* d_in, const int* in_sizes, int n_in,
                              void* d_out, int out_size, void* d_ws, size_t ws_size,
                              hipStream_t stream) {
    (void)in_sizes; (void)n_in; (void)out_size; (void)ws_size; // needs ws_size >= 20051968
    const float* x  = (const float*)d_in[0];
    const float* Wq = (const float*)d_in[1];
    const float* bq = (const float*)d_in[2];
    const float* Wk = (const float*)d_in[3];
    const float* bk = (const float*)d_in[4];
    const float* Wv = (const float*)d_in[5];
    const float* bv = (const float*)d_in[6];
    const float* Wp = (const float*)d_in[7];
    const float* bp = (const float*)d_in[8];
    char* ws = (char*)d_ws;

    convert_pre<<<dim3(2048), dim3(256), 0, stream>>>(x, Wq, Wk, Wv, Wp, ws);
    hipFuncSetAttribute((const void*)mha_fused,
                        hipFuncAttributeMaxDynamicSharedMemorySize, LDS_SIZE);
    mha_fused<<<dim3(2048), dim3(512), LDS_SIZE, stream>>>(
        ws, bq, bk, bv, bp, (float*)d_out);
}